// Round 6
// baseline (214.244 us; speedup 1.0000x reference)
//
#include <hip/hip_runtime.h>
#include <math.h>

#define NUM_CLASSES 27
#define HDIM 256
#define WDIM 256
#define NPIX (HDIM * WDIM)

// Fixed problem shape: B=16, M=32, H=W=256.
// Hist blocks: 256 threads, 28.7 KB LDS -> 5 blocks/CU (20 waves/CU).
// Each (b,m) histogram is split into NCH pixel-chunks (NCH=4 when ws allows)
// so 2048 hist blocks keep every CU's LDS-residency slots full and the
// per-thread serial ds RMW chain is only 16 iterations deep.
#define NB_BND 1024              // B*HDIM/4 blocks, 4 rows each (1 row/wave)
#define ROWS_PER_BND_BLOCK 4

// ws layout (floats), nch = chunks per (b,m) (4 or 1):
//   [0 .. 512*nch*28)          : partial class histograms, (bm*nch+q)*28 + c
//   nbase = 512*nch*28
//   [nbase        .. +1024)    : intersection per boundary block
//   [nbase+1024   .. +2048)    : union per boundary block
//   [nbase+2048   .. +3072)    : dbc-term sum per boundary block
// All slots written every launch (no zeroing needed).
//
// Post-mortem ledger (do not regress):
//  - R1: atomicAdd on a GENERIC float* into LDS -> CAS/flat path, 3x regression.
//  - R2: single-kernel finalize via per-block agent-scope ACQ_REL fetch_add ->
//    per-block L2 cache ops, 2.5x regression. Two-kernel form keeps the free
//    kernel-boundary release/acquire.
//  - R4/R5: workgroup-scope __hip_atomic_fetch_add on LDS -> container failed
//    twice (likely GPU hang). Construct is banned; plain += is the proven form.
//  - R5: latency fix is PARALLELISM (4x hist blocks, 1/4 chain depth), not
//    fire-and-forget atomics.

__global__ __launch_bounds__(256) void fused_kernel(
    const float* __restrict__ masks, const int* __restrict__ sem,
    const float* __restrict__ depth, float* __restrict__ ws, int M, int nch) {
  // Conflict-free layout: bin c of thread t at s_hist[c][t].
  // Row stride = 256 floats (== 0 mod 32 banks), so bank = t & 31:
  // class-independent, exactly 2 lanes/bank per wave access -> free (m136).
  __shared__ float s_hist[28][256];  // 28.7 KB
  __shared__ float s_part[8][32];
  __shared__ float s_i[4], s_u[4], s_t[4];

  const int tid = threadIdx.x;
  const int nhb = nch << 9;  // 512*nch hist blocks

  if ((int)blockIdx.x < nhb) {
    // -------- partial histogram for one (b,m), pixel-chunk q --------
    const int bm = blockIdx.x & 511;
    const int q = blockIdx.x >> 9;
    const int b = bm / M;
    const int m = bm % M;

#pragma unroll
    for (int c = 0; c < 28; ++c) s_hist[c][tid] = 0.0f;
    // no sync needed: hot loop touches only this thread's own column

    const float4* __restrict__ m4 =
        (const float4*)(masks + ((size_t)b * M + m) * (size_t)NPIX);
    const int4* __restrict__ s4 = (const int4*)(sem + (size_t)b * (size_t)NPIX);

    const int itpc = 64 / nch;  // iterations per chunk (NPIX/4/256 = 64 total)
    const int it0 = q * itpc;
    for (int it = it0; it < it0 + itpc; ++it) {
      const int idx = it * 256 + tid;
      const float4 mv = m4[idx];
      const int4 cv = s4[idx];
      s_hist[cv.x][tid] += mv.x;
      s_hist[cv.y][tid] += mv.y;
      s_hist[cv.z][tid] += mv.z;
      s_hist[cv.w][tid] += mv.w;
    }
    __syncthreads();

    // stage 2: thread (c = tid&31, s = tid>>5) sums bin c over 32 columns.
    // Skew iteration by c so banks stay spread (2-way only).
    {
      const int c = tid & 31;
      const int s = tid >> 5;  // 8 groups of 32 columns
      if (c < 28) {
        float acc = 0.f;
#pragma unroll
        for (int i = 0; i < 32; ++i)
          acc += s_hist[c][s * 32 + ((i + c) & 31)];
        s_part[s][c] = acc;
      }
    }
    __syncthreads();

    // stage 3: write 28 partial bins for this chunk (entropy moves to finalize)
    if (tid < 28) {
      float tot = 0.f;
#pragma unroll
      for (int g = 0; g < 8; ++g) tot += s_part[g][tid];
      ws[((size_t)bm * nch + q) * 28 + tid] = tot;
    }
  } else {
    // ---------------- boundary IoU + depth coherence: 4 rows/block ----------------
    const int j = blockIdx.x - nhb;
    const int wave = tid >> 6;
    const int lane = tid & 63;
    const int brow = j * ROWS_PER_BND_BLOCK + wave;  // all 4 rows share b
    const int b = brow >> 8;
    const int y = brow & 255;

    const size_t rowoff = (size_t)b * NPIX + (size_t)y * WDIM;
    const float4* mp = (const float4*)(masks + (size_t)b * M * NPIX + (size_t)y * WDIM);
    const float4* dp = (const float4*)(depth + rowoff);
    const int4* sp = (const int4*)(sem + rowoff);

    const int uoff = (y > 0) ? -(WDIM / 4) : 0;

    const float4 mv = mp[lane];
    const float4 mvu = mp[lane + uoff];
    const float4 dv = dp[lane];
    const float4 dvu = dp[lane + uoff];
    const int4 sv = sp[lane];
    const int4 svu = sp[lane + uoff];

    const int src = (lane > 0) ? (lane - 1) : 0;
    float mw = __shfl(mv.w, src);
    float dw = __shfl(dv.w, src);
    int swv = __shfl(sv.w, src);
    if (lane == 0) { mw = mv.x; dw = dv.x; swv = sv.x; }

    const float ml[4] = {mw, mv.x, mv.y, mv.z};
    const float dl[4] = {dw, dv.x, dv.y, dv.z};
    const int sl[4] = {swv, sv.x, sv.y, sv.z};
    const float mc[4] = {mv.x, mv.y, mv.z, mv.w};
    const float dc[4] = {dv.x, dv.y, dv.z, dv.w};
    const int sc[4] = {sv.x, sv.y, sv.z, sv.w};
    const float mu[4] = {mvu.x, mvu.y, mvu.z, mvu.w};
    const float du[4] = {dvu.x, dvu.y, dvu.z, dvu.w};
    const int su[4] = {svu.x, svu.y, svu.z, svu.w};

    float inter = 0.f, uni = 0.f, term = 0.f;
#pragma unroll
    for (int k = 0; k < 4; ++k) {
      const bool semb = (sc[k] != sl[k]) || (sc[k] != su[k]);
      const bool instb = (fabsf(mc[k] - ml[k]) > 0.3f) || (fabsf(mc[k] - mu[k]) > 0.3f);
      inter += (semb && instb) ? 1.0f : 0.0f;
      uni += (semb || instb) ? 1.0f : 0.0f;
      const float gx = dc[k] - dl[k];
      const float gy = dc[k] - du[k];
      const float db = sqrtf(fmaxf(gx * gx + gy * gy, 1e-24f));
      const float dbc = fminf(db, 2.0f);
      term += semb ? 0.0f : (1.0f + 3.0f * dbc) * dbc;
    }

    for (int off = 32; off > 0; off >>= 1) {
      inter += __shfl_down(inter, off);
      uni += __shfl_down(uni, off);
      term += __shfl_down(term, off);
    }
    if (lane == 0) { s_i[wave] = inter; s_u[wave] = uni; s_t[wave] = term; }
    __syncthreads();
    if (tid == 0) {
      float bi = 0.f, bu = 0.f, bt = 0.f;
#pragma unroll
      for (int w = 0; w < 4; ++w) { bi += s_i[w]; bu += s_u[w]; bt += s_t[w]; }
      const int nbase = nhb * 28;
      ws[nbase + j] = bi;
      ws[nbase + 1024 + j] = bu;
      ws[nbase + 2048 + j] = bt;
    }
  }
}

// ---------------- finalize: entropy per (b,m) + reduce all partials ----------------
__global__ __launch_bounds__(512) void finalize_kernel(
    const float* __restrict__ ws, float* __restrict__ out, int B, int M, int nch) {
  const int tid = threadIdx.x;
  const int lane = tid & 63;
  const int wave = tid >> 6;
  __shared__ float s_e[8], s_d[8], s_r[16];

  // ---- entropy for (b,m) = tid: sum nch partial histograms, then entropy ----
  float bins[28];
#pragma unroll
  for (int c = 0; c < 28; ++c) bins[c] = 0.f;
  for (int q = 0; q < nch; ++q) {
    const size_t base = ((size_t)tid * nch + q) * 28;
#pragma unroll
    for (int c = 0; c < 28; ++c) bins[c] += ws[base + c];
  }
  float ms = 0.f;
#pragma unroll
  for (int c = 0; c < 28; ++c) ms += bins[c];
  ms += 1e-6f;
  float ent = 0.f;
#pragma unroll
  for (int c = 0; c < NUM_CLASSES; ++c) {
    const float p = fminf(fmaxf(bins[c] / ms, 1e-7f), 1.0f);
    if (p > 1e-6f) ent += p * logf(p + 1e-10f);
  }
  float e = -ent;

  // ---- boundary partials: 1024 each; thread tid takes pair (2*tid, 2*tid+1).
  // Pair shares the same image b: b = j/64 = tid/32, so threads
  // [32b, 32b+32) cover exactly image b's 64 boundary blocks.
  const int nbase = (nch << 9) * 28;
  float inter = ws[nbase + 2 * tid] + ws[nbase + 2 * tid + 1];
  float uni = ws[nbase + 1024 + 2 * tid] + ws[nbase + 1024 + 2 * tid + 1];
  float dbc = ws[nbase + 2048 + 2 * tid] + ws[nbase + 2048 + 2 * tid + 1];

  for (int off = 16; off > 0; off >>= 1) {
    inter += __shfl_down(inter, off, 32);
    uni += __shfl_down(uni, off, 32);
  }
  if ((tid & 31) == 0) s_r[tid >> 5] = inter / (uni + 1e-8f);

  for (int off = 32; off > 0; off >>= 1) {
    e += __shfl_down(e, off);
    dbc += __shfl_down(dbc, off);
  }
  if (lane == 0) { s_e[wave] = e; s_d[wave] = dbc; }
  __syncthreads();

  if (tid == 0) {
    float se = 0.f, sd = 0.f, sr = 0.f;
#pragma unroll
    for (int w = 0; w < 8; ++w) { se += s_e[w]; sd += s_d[w]; }
#pragma unroll
    for (int b = 0; b < 16; ++b) sr += s_r[b];
    const float l_u = se / ((float)(B * M) + 1e-8f);
    const float l_b = 1.0f - sr / (float)B;
    const float l_d = sd / (float)((size_t)B * NPIX);
    out[0] = l_u;
    out[1] = l_b;
    out[2] = l_d;
    out[3] = 0.3f * l_u + 0.2f * l_b + 0.2f * l_d;
  }
}

extern "C" void kernel_launch(void* const* d_in, const int* in_sizes, int n_in,
                              void* d_out, int out_size, void* d_ws, size_t ws_size,
                              hipStream_t stream) {
  const int* sem = (const int*)d_in[0];        // (B, N) int32
  const float* masks = (const float*)d_in[1];  // (B, M, N) f32
  const float* depth = (const float*)d_in[2];  // (B, N) f32

  const int B = in_sizes[0] / NPIX;         // 16
  const int M = in_sizes[1] / in_sizes[0];  // 32
  float* ws = (float*)d_ws;
  float* out = (float*)d_out;

  // 4-chunk split needs 512*4*28 + 3072 = 60416 floats of ws; fall back to the
  // R3-equivalent 1-chunk layout if the workspace is smaller (evidence says
  // ws is ~512 MiB, so nch=4 in practice).
  const int nch = (ws_size >= 60416u * sizeof(float)) ? 4 : 1;

  fused_kernel<<<512 * nch + NB_BND, 256, 0, stream>>>(masks, sem, depth, ws, M, nch);
  finalize_kernel<<<1, 512, 0, stream>>>(ws, out, B, M, nch);
}